// Round 7
// baseline (270.307 us; speedup 1.0000x reference)
//
#include <hip/hip_runtime.h>

#define BATCH 4
#define SEQ   1024
#define EMB   256
#define NH    12
#define EH    3072   // EMB*NH
#define MROWS 4096   // BATCH*SEQ

typedef __attribute__((ext_vector_type(8))) short bf16x8;
typedef __attribute__((ext_vector_type(4))) float f32x4;
typedef __attribute__((ext_vector_type(4))) short short4v;

__device__ __forceinline__ short f2bf(float f) {
  union { float f; unsigned u; } x; x.f = f;
  unsigned r = x.u + 0x7fffu + ((x.u >> 16) & 1u);  // round-to-nearest-even
  return (short)(r >> 16);
}

__device__ __forceinline__ void gload_lds16(const void* g, void* l) {
  __builtin_amdgcn_global_load_lds(
      (const __attribute__((address_space(1))) unsigned*)g,
      (__attribute__((address_space(3))) unsigned*)l, 16, 0, 0);
}

// ---------------- cast x (fp32 -> bf16) ----------------
__global__ __launch_bounds__(256) void cast_x_kernel(const float* __restrict__ in,
                                                     short* __restrict__ out) {
  int i = (blockIdx.x * 256 + threadIdx.x) * 4;
  float4 v = *(const float4*)(in + i);
  short4v o;
  o[0] = f2bf(v.x); o[1] = f2bf(v.y); o[2] = f2bf(v.z); o[3] = f2bf(v.w);
  *(short4v*)(out + i) = o;
}

// ------- transpose + cast, fused QKV: z selects Wq/Wk/Wv (all [EMB][EH]) -------
__global__ __launch_bounds__(256) void transpose_qkv_kernel(const float* __restrict__ Wq,
                                                            const float* __restrict__ Wk,
                                                            const float* __restrict__ Wv,
                                                            short* __restrict__ Wt) {
  __shared__ float tile[32][33];
  const float* W = blockIdx.z == 0 ? Wq : (blockIdx.z == 1 ? Wk : Wv);
  short* o = Wt + (size_t)blockIdx.z * EH * EMB;
  const int n0 = blockIdx.x * 32, k0 = blockIdx.y * 32;
  const int tx = threadIdx.x & 31, ty = threadIdx.x >> 5;  // 32 x 8
#pragma unroll
  for (int i = 0; i < 4; i++)
    tile[ty + 8 * i][tx] = W[(size_t)(k0 + ty + 8 * i) * EH + n0 + tx];
  __syncthreads();
#pragma unroll
  for (int i = 0; i < 4; i++) {
    int nr = ty + 8 * i;
    o[(size_t)(n0 + nr) * EMB + k0 + tx] = f2bf(tile[tx][nr]);
  }
}

// ---------------- generic transpose + cast W[K][N] -> Wt[N][K] ----------------
__global__ __launch_bounds__(256) void transpose_cast_kernel(const float* __restrict__ W,
                                                             short* __restrict__ Wt,
                                                             int K, int N) {
  __shared__ float tile[32][33];
  const int n0 = blockIdx.x * 32, k0 = blockIdx.y * 32;
  const int tx = threadIdx.x & 31, ty = threadIdx.x >> 5;
#pragma unroll
  for (int i = 0; i < 4; i++)
    tile[ty + 8 * i][tx] = W[(size_t)(k0 + ty + 8 * i) * N + n0 + tx];
  __syncthreads();
#pragma unroll
  for (int i = 0; i < 4; i++) {
    int nr = ty + 8 * i;
    Wt[(size_t)(n0 + nr) * K + k0 + tx] = f2bf(tile[tx][nr]);
  }
}

// ------- fused QKV GEMM: C[4096][9216] = xb * WqkvT^T, region epilogues -------
// region 0: q row-major, PRE-SCALED by log2(e)/16; region 1: k row-major;
// region 2: v -> [b][h][d][s].
__global__ __launch_bounds__(256) void qkv_gemm_kernel(const short* __restrict__ A,
                                                       const short* __restrict__ Bt,
                                                       const float* __restrict__ bq,
                                                       const float* __restrict__ bk,
                                                       const float* __restrict__ bv,
                                                       short* __restrict__ qout,
                                                       short* __restrict__ kout,
                                                       short* __restrict__ vout) {
  constexpr int BM = 128, BN = 128, BK = 32, K = EMB;
  constexpr int WM = 64, WN = 64, MT = 4, NT = 4;
  __shared__ short As[BM * BK];
  __shared__ short Bs[BN * BK];
  const int tid = threadIdx.x;
  const int w = tid >> 6, lane = tid & 63;
  const int wm = w >> 1, wn = w & 1;
  const int l15 = lane & 15, l4 = lane >> 4;
  const int m0 = blockIdx.x * BM, n0 = blockIdx.y * BN;

  f32x4 acc[MT][NT] = {};
  const int crow = lane >> 2;
  const int ckb  = (lane & 3) * 16;

  for (int k0 = 0; k0 < K; k0 += BK) {
#pragma unroll
    for (int i = 0; i < 2; i++) {
      int c = w + i * 4;
      gload_lds16((const char*)(A + (size_t)(m0 + c * 16 + crow) * K + k0) + ckb,
                  (char*)As + c * 1024);
      gload_lds16((const char*)(Bt + (size_t)(n0 + c * 16 + crow) * K + k0) + ckb,
                  (char*)Bs + c * 1024);
    }
    asm volatile("s_waitcnt vmcnt(0)" ::: "memory");
    __syncthreads();

    bf16x8 af[MT], bfr[NT];
#pragma unroll
    for (int mt = 0; mt < MT; mt++)
      af[mt] = *(const bf16x8*)&As[(wm * WM + mt * 16 + l15) * BK + 8 * l4];
#pragma unroll
    for (int nt = 0; nt < NT; nt++)
      bfr[nt] = *(const bf16x8*)&Bs[(wn * WN + nt * 16 + l15) * BK + 8 * l4];
#pragma unroll
    for (int mt = 0; mt < MT; mt++)
#pragma unroll
      for (int nt = 0; nt < NT; nt++)
        acc[mt][nt] = __builtin_amdgcn_mfma_f32_16x16x32_bf16(af[mt], bfr[nt], acc[mt][nt], 0, 0, 0);
    __syncthreads();
  }

  const int region = n0 / 3072;  // block-uniform (3072 % 128 == 0)
  const float* bias = region == 0 ? bq : (region == 1 ? bk : bv);
  const float kQScale = 0.09016844f;  // (1/16) * log2(e), folded into Q
#pragma unroll
  for (int nt = 0; nt < NT; nt++) {
    const int n = n0 + wn * WN + nt * 16 + l15;
    const int col = n - region * 3072;
    const float bvv = bias[col];
#pragma unroll
    for (int mt = 0; mt < MT; mt++) {
      const int mrow = m0 + wm * WM + mt * 16 + 4 * l4;
      f32x4 v = acc[mt][nt];
      if (region == 0) {
#pragma unroll
        for (int r = 0; r < 4; r++)
          qout[(size_t)(mrow + r) * EH + col] = f2bf((v[r] + bvv) * kQScale);
      } else if (region == 1) {
#pragma unroll
        for (int r = 0; r < 4; r++)
          kout[(size_t)(mrow + r) * EH + col] = f2bf(v[r] + bvv);
      } else {
        const int bb = mrow >> 10;
        const int s  = mrow & 1023;
        const int h  = col >> 8, d = col & 255;
        short4v o4;
        o4[0] = f2bf(v[0] + bvv); o4[1] = f2bf(v[1] + bvv);
        o4[2] = f2bf(v[2] + bvv); o4[3] = f2bf(v[3] + bvv);
        *(short4v*)&vout[((size_t)(bb * NH + h) * EMB + d) * SEQ + s] = o4;
      }
    }
  }
}

// ---------------- fc GEMM: out[M][N] = ctx * WfcT^T + bias (fp32 out) ----------------
__global__ __launch_bounds__(256) void fc_gemm_kernel(const short* __restrict__ A,
                                                      const short* __restrict__ Bt,
                                                      const float* __restrict__ bias,
                                                      float* __restrict__ Cout,
                                                      int M, int N, int K) {
  constexpr int BM = 64, BN = 64, BK = 32;
  constexpr int WM = 32, WN = 32, MT = 2, NT = 2;
  __shared__ short As[BM * BK];
  __shared__ short Bs[BN * BK];
  const int tid = threadIdx.x;
  const int w = tid >> 6, lane = tid & 63;
  const int wm = w >> 1, wn = w & 1;
  const int l15 = lane & 15, l4 = lane >> 4;
  const int m0 = blockIdx.x * BM, n0 = blockIdx.y * BN;

  f32x4 acc[MT][NT] = {};
  const int crow = lane >> 2;
  const int ckb  = (lane & 3) * 16;

  for (int k0 = 0; k0 < K; k0 += BK) {
    {
      int c = w;
      gload_lds16((const char*)(A + (size_t)(m0 + c * 16 + crow) * K + k0) + ckb,
                  (char*)As + c * 1024);
      gload_lds16((const char*)(Bt + (size_t)(n0 + c * 16 + crow) * K + k0) + ckb,
                  (char*)Bs + c * 1024);
    }
    asm volatile("s_waitcnt vmcnt(0)" ::: "memory");
    __syncthreads();

    bf16x8 af[MT], bfr[NT];
#pragma unroll
    for (int mt = 0; mt < MT; mt++)
      af[mt] = *(const bf16x8*)&As[(wm * WM + mt * 16 + l15) * BK + 8 * l4];
#pragma unroll
    for (int nt = 0; nt < NT; nt++)
      bfr[nt] = *(const bf16x8*)&Bs[(wn * WN + nt * 16 + l15) * BK + 8 * l4];
#pragma unroll
    for (int mt = 0; mt < MT; mt++)
#pragma unroll
      for (int nt = 0; nt < NT; nt++)
        acc[mt][nt] = __builtin_amdgcn_mfma_f32_16x16x32_bf16(af[mt], bfr[nt], acc[mt][nt], 0, 0, 0);
    __syncthreads();
  }

#pragma unroll
  for (int nt = 0; nt < NT; nt++) {
    const int n = n0 + wn * WN + nt * 16 + l15;
    const float bvv = bias[n];
#pragma unroll
    for (int mt = 0; mt < MT; mt++) {
      const int mrow = m0 + wm * WM + mt * 16 + 4 * l4;
      f32x4 v = acc[mt][nt];
#pragma unroll
      for (int r = 0; r < 4; r++)
        Cout[(size_t)(mrow + r) * N + n] = v[r] + bvv;
    }
  }
}

// ---------------- causal flash attention (dbuf K, V direct, swizzled) --------
// grid (BATCH*NH, SEQ/64), q-tile = 15 - blockIdx.y (heavy-first packing).
// KVBLK = 32. K tile double-buffered in LDS via global_load_lds with
// pre-swizzled SOURCE address (G21): layout [buf][kstp][kv][128B row of 8
// segs], phys seg = lseg ^ (kv&7) -> ds_read_b128 conflict-free.
// V read direct from global (L2-resident, m169). One vmcnt(0)+barrier/tile;
// next tile's stage issued BEFORE compute (T3 minimal 2-phase).
// Q pre-scaled by log2(e)/16; exp2-domain softmax, defer-rescale,
// distributed l-state, diagonal-only masking.
__global__ __launch_bounds__(256) void attn_kernel(const short* __restrict__ Q,
                                                   const short* __restrict__ Kg,
                                                   const short* __restrict__ Vt,
                                                   short* __restrict__ Ctx) {
  __shared__ short Ks[2 * 8192];      // 2 x 16 KB
  __shared__ short Ps[4 * 16 * 32];   // 4 KB, per-wave, seg-swizzled
  const int tid = threadIdx.x, w = tid >> 6, lane = tid & 63;
  const int l15 = lane & 15, l4 = lane >> 4;
  const int bh = blockIdx.x, b = bh / NH, h = bh % NH;
  const int qt = (gridDim.y - 1) - blockIdx.y;   // heavy-first
  const int q0 = qt * 64;
  const int ntiles = 2 * qt + 2;

  const float kMaskL2 = -14426.95f;   // -10000 * log2(e)
  const float kThrL2  = 11.5f;        // ~8 nats defer threshold

  const short* Kbase = Kg + (size_t)b * SEQ * EH + h * EMB;
  const short* Vbase = Vt + (size_t)bh * EMB * SEQ;

  // ---- stage geometry: 4 issues/thread, idx in [0,1024): 16B each ----
  // idx -> kstp = idx>>8, kv = (idx>>3)&31, lseg = idx&7; LDS byte = idx*16.
  // source d-col (shorts) = kstp*64 + ((lseg ^ (kv&7)) << 3)   [swizzled src]
  int s_kv[4], s_col[4];
#pragma unroll
  for (int i = 0; i < 4; i++) {
    const int idx = i * 256 + tid;
    s_kv[i]  = (idx >> 3) & 31;
    s_col[i] = ((idx >> 8) << 6) + (((idx & 7) ^ (s_kv[i] & 7)) << 3);
  }

  // ---- Q fragments (issued first; latency overlaps prologue staging) ----
  bf16x8 qf[8];
  {
    const short* qp = Q + (size_t)(b * SEQ + q0 + w * 16 + l15) * EH + h * EMB + 8 * l4;
#pragma unroll
    for (int kst = 0; kst < 8; kst++) qf[kst] = *(const bf16x8*)(qp + 32 * kst);
  }

  // ---- prologue: stage tile 0 into buf 0 ----
#pragma unroll
  for (int i = 0; i < 4; i++)
    gload_lds16(Kbase + (size_t)s_kv[i] * EH + s_col[i],
                (char*)Ks + (i * 256 + tid) * 16);
  asm volatile("s_waitcnt vmcnt(0)" ::: "memory");
  __syncthreads();

  f32x4 o[16] = {};
  float mst[4], lst[4];
#pragma unroll
  for (int r = 0; r < 4; r++) { mst[r] = -1e30f; lst[r] = 0.f; }

  int buf = 0;
  for (int t = 0; t < ntiles; t++) {
    const int kv0 = t * 32;

    // ---- issue next-tile K stage into buf^1 (completes during compute) ----
    if (t + 1 < ntiles) {
      const short* kp = Kbase + (size_t)(kv0 + 32) * EH;
#pragma unroll
      for (int i = 0; i < 4; i++)
        gload_lds16(kp + (size_t)s_kv[i] * EH + s_col[i],
                    (char*)Ks + (buf ^ 1) * 16384 + (i * 256 + tid) * 16);
    }

    // ---- S = Q K^T (reads conflict-free: seg ^ (l15&7)) ----
    f32x4 sf[2] = {};
    const short* ksb = Ks + buf * 8192;
    __builtin_amdgcn_s_setprio(1);
#pragma unroll
    for (int nt = 0; nt < 2; nt++)
#pragma unroll
      for (int kst = 0; kst < 8; kst++) {
        const int seg = (((kst & 1) << 2) + l4) ^ (l15 & 7);
        bf16x8 kf = *(const bf16x8*)&ksb[(kst >> 1) * 2048 + (nt * 16 + l15) * 64 + seg * 8];
        sf[nt] = __builtin_amdgcn_mfma_f32_16x16x32_bf16(qf[kst], kf, sf[nt], 0, 0, 0);
      }
    __builtin_amdgcn_s_setprio(0);

    // ---- online softmax (exp2 domain, Q pre-scaled, distributed l) ----
    const bool maskt = (t >= 2 * qt);   // only the 2 diagonal tiles mask
    float pp[2][4];
    float fsc[4];
    bool skip[4];
#pragma unroll
    for (int r = 0; r < 4; r++) {
      float sc[2];
      float mx = -1e30f;
#pragma unroll
      for (int nt = 0; nt < 2; nt++) {
        float s = sf[nt][r];
        if (maskt) {
          const int qrow = q0 + w * 16 + 4 * l4 + r;
          s += (kv0 + nt * 16 + l15 > qrow) ? kMaskL2 : 0.0f;
        }
        sc[nt] = s;
        mx = fmaxf(mx, s);
      }
      mx = fmaxf(mx, __shfl_xor(mx, 1));
      mx = fmaxf(mx, __shfl_xor(mx, 2));
      mx = fmaxf(mx, __shfl_xor(mx, 4));
      mx = fmaxf(mx, __shfl_xor(mx, 8));
      skip[r] = __all(mx <= mst[r] + kThrL2);
      float mref;
      if (skip[r]) {
        fsc[r] = 1.0f;
        mref = mst[r];
      } else {
        float mnew = fmaxf(mst[r], mx);
        fsc[r] = exp2f(mst[r] - mnew);
        mst[r] = mnew;
        mref = mnew;
      }
      float rs = 0.f;
#pragma unroll
      for (int nt = 0; nt < 2; nt++) {
        float e = exp2f(sc[nt] - mref);
        pp[nt][r] = e;
        rs += e;
      }
      lst[r] = lst[r] * fsc[r] + rs;   // per-lane partial; reduced at the end
    }
#pragma unroll
    for (int r = 0; r < 4; r++) {
      if (!skip[r]) {
#pragma unroll
        for (int nt = 0; nt < 16; nt++) o[nt][r] *= fsc[r];
      }
    }

    // ---- P -> per-wave LDS [16][32], seg ^= (row>>1)&3 (2-way, free) ----
#pragma unroll
    for (int nt = 0; nt < 2; nt++)
#pragma unroll
      for (int r = 0; r < 4; r++) {
        const int prow = 4 * l4 + r;
        const int col  = nt * 16 + l15;
        const int pseg = (col >> 3) ^ ((prow >> 1) & 3);
        Ps[w * 512 + prow * 32 + pseg * 8 + (col & 7)] = f2bf(pp[nt][r]);
      }

    // ---- O += P V  (V direct from global; L2-resident) ----
    {
      const int aseg = l4 ^ ((l15 >> 1) & 3);
      bf16x8 af = *(const bf16x8*)&Ps[w * 512 + l15 * 32 + aseg * 8];
      const short* vp = Vbase + kv0 + 8 * l4;
      __builtin_amdgcn_s_setprio(1);
#pragma unroll
      for (int half = 0; half < 2; half++) {
        bf16x8 vfs[8];
#pragma unroll
        for (int j = 0; j < 8; j++)
          vfs[j] = *(const bf16x8*)(vp + (size_t)((half * 8 + j) * 16 + l15) * SEQ);
#pragma unroll
        for (int j = 0; j < 8; j++)
          o[half * 8 + j] = __builtin_amdgcn_mfma_f32_16x16x32_bf16(af, vfs[j], o[half * 8 + j], 0, 0, 0);
      }
      __builtin_amdgcn_s_setprio(0);
    }

    // ---- single per-tile sync: stage writes done + all Ks reads done ----
    asm volatile("s_waitcnt vmcnt(0)" ::: "memory");
    __syncthreads();
    buf ^= 1;
  }

  // ---- reduce distributed l, normalize, store ctx ----
  float inv[4];
#pragma unroll
  for (int r = 0; r < 4; r++) {
    float rs = lst[r];
    rs += __shfl_xor(rs, 1);
    rs += __shfl_xor(rs, 2);
    rs += __shfl_xor(rs, 4);
    rs += __shfl_xor(rs, 8);
    inv[r] = 1.f / rs;
  }
  const int mrow = b * SEQ + q0 + w * 16 + 4 * l4;
#pragma unroll
  for (int nt = 0; nt < 16; nt++) {
    const int d = h * EMB + nt * 16 + l15;
#pragma unroll
    for (int r = 0; r < 4; r++)
      Ctx[(size_t)(mrow + r) * EH + d] = f2bf(o[nt][r] * inv[r]);
  }
}

extern "C" void kernel_launch(void* const* d_in, const int* in_sizes, int n_in,
                              void* d_out, int out_size, void* d_ws, size_t ws_size,
                              hipStream_t stream) {
  const float* x   = (const float*)d_in[0];
  const float* Wq  = (const float*)d_in[2];
  const float* bq  = (const float*)d_in[3];
  const float* Wk  = (const float*)d_in[4];
  const float* bk  = (const float*)d_in[5];
  const float* Wv  = (const float*)d_in[6];
  const float* bv  = (const float*)d_in[7];
  const float* Wfc = (const float*)d_in[8];
  const float* bfc = (const float*)d_in[9];
  float* out = (float*)d_out;

  short* ws    = (short*)d_ws;
  short* xb    = ws;                  // 4096*256
  short* wqkvt = xb + 1048576;        // 3*3072*256 contiguous [9216][256]
  short* wfct  = wqkvt + 3 * 786432;  // 256*3072
  short* q     = wfct + 786432;       // 4096*3072 (pre-scaled by log2e/16)
  short* k     = q + 12582912;
  short* vt    = k + 12582912;        // [b][h][d][s]
  short* ctx   = vt + 12582912;       // 4096*3072

  cast_x_kernel<<<1024, 256, 0, stream>>>(x, xb);
  transpose_qkv_kernel<<<dim3(EH / 32, EMB / 32, 3), 256, 0, stream>>>(Wq, Wk, Wv, wqkvt);
  transpose_cast_kernel<<<dim3(EMB / 32, EH / 32), 256, 0, stream>>>(Wfc, wfct, EH, EMB);

  qkv_gemm_kernel<<<dim3(MROWS / 128, 9216 / 128), 256, 0, stream>>>(
      xb, wqkvt, bq, bk, bv, q, k, vt);

  attn_kernel<<<dim3(BATCH * NH, SEQ / 64), 256, 0, stream>>>(q, k, vt, ctx);

  fc_gemm_kernel<<<dim3(MROWS / 64, EMB / 64), 256, 0, stream>>>(ctx, wfct, bfc, out, MROWS, EMB, EH);
}

// Round 8
// 179.064 us; speedup vs baseline: 1.5096x; 1.5096x over previous
//
#include <hip/hip_runtime.h>

#define BATCH 4
#define SEQ   1024
#define EMB   256
#define NH    12
#define EH    3072   // EMB*NH
#define MROWS 4096   // BATCH*SEQ

typedef __attribute__((ext_vector_type(8))) short bf16x8;
typedef __attribute__((ext_vector_type(4))) float f32x4;
typedef __attribute__((ext_vector_type(4))) short short4v;

__device__ __forceinline__ short f2bf(float f) {
  union { float f; unsigned u; } x; x.f = f;
  unsigned r = x.u + 0x7fffu + ((x.u >> 16) & 1u);  // round-to-nearest-even
  return (short)(r >> 16);
}

__device__ __forceinline__ void gload_lds16(const void* g, void* l) {
  __builtin_amdgcn_global_load_lds(
      (const __attribute__((address_space(1))) unsigned*)g,
      (__attribute__((address_space(3))) unsigned*)l, 16, 0, 0);
}

// ---------------- cast x (fp32 -> bf16) ----------------
__global__ __launch_bounds__(256) void cast_x_kernel(const float* __restrict__ in,
                                                     short* __restrict__ out) {
  int i = (blockIdx.x * 256 + threadIdx.x) * 4;
  float4 v = *(const float4*)(in + i);
  short4v o;
  o[0] = f2bf(v.x); o[1] = f2bf(v.y); o[2] = f2bf(v.z); o[3] = f2bf(v.w);
  *(short4v*)(out + i) = o;
}

// ------- transpose + cast, fused QKV: z selects Wq/Wk/Wv (all [EMB][EH]) -------
__global__ __launch_bounds__(256) void transpose_qkv_kernel(const float* __restrict__ Wq,
                                                            const float* __restrict__ Wk,
                                                            const float* __restrict__ Wv,
                                                            short* __restrict__ Wt) {
  __shared__ float tile[32][33];
  const float* W = blockIdx.z == 0 ? Wq : (blockIdx.z == 1 ? Wk : Wv);
  short* o = Wt + (size_t)blockIdx.z * EH * EMB;
  const int n0 = blockIdx.x * 32, k0 = blockIdx.y * 32;
  const int tx = threadIdx.x & 31, ty = threadIdx.x >> 5;  // 32 x 8
#pragma unroll
  for (int i = 0; i < 4; i++)
    tile[ty + 8 * i][tx] = W[(size_t)(k0 + ty + 8 * i) * EH + n0 + tx];
  __syncthreads();
#pragma unroll
  for (int i = 0; i < 4; i++) {
    int nr = ty + 8 * i;
    o[(size_t)(n0 + nr) * EMB + k0 + tx] = f2bf(tile[tx][nr]);
  }
}

// ---------------- generic transpose + cast W[K][N] -> Wt[N][K] ----------------
__global__ __launch_bounds__(256) void transpose_cast_kernel(const float* __restrict__ W,
                                                             short* __restrict__ Wt,
                                                             int K, int N) {
  __shared__ float tile[32][33];
  const int n0 = blockIdx.x * 32, k0 = blockIdx.y * 32;
  const int tx = threadIdx.x & 31, ty = threadIdx.x >> 5;
#pragma unroll
  for (int i = 0; i < 4; i++)
    tile[ty + 8 * i][tx] = W[(size_t)(k0 + ty + 8 * i) * N + n0 + tx];
  __syncthreads();
#pragma unroll
  for (int i = 0; i < 4; i++) {
    int nr = ty + 8 * i;
    Wt[(size_t)(n0 + nr) * K + k0 + tx] = f2bf(tile[tx][nr]);
  }
}

// ------- fused QKV GEMM: C[4096][9216] = xb * WqkvT^T, region epilogues -------
// BM=BN=128, BK=32, DOUBLE-BUFFERED (T3 2-phase), row-pair XOR-swizzled LDS
// (conflict-free ds_read_b128). region 0: q (pre-scaled log2e/16); 1: k;
// 2: v -> [b][h][d][s].
__global__ __launch_bounds__(256) void qkv_gemm_kernel(const short* __restrict__ A,
                                                       const short* __restrict__ Bt,
                                                       const float* __restrict__ bq,
                                                       const float* __restrict__ bk,
                                                       const float* __restrict__ bv,
                                                       short* __restrict__ qout,
                                                       short* __restrict__ kout,
                                                       short* __restrict__ vout) {
  constexpr int BM = 128, BN = 128, BK = 32, K = EMB;
  __shared__ short As[2][BM * BK];
  __shared__ short Bs[2][BN * BK];
  const int tid = threadIdx.x;
  const int w = tid >> 6, lane = tid & 63;
  const int wm = w >> 1, wn = w & 1;
  const int l15 = lane & 15, l4 = lane >> 4;
  const int m0 = blockIdx.x * BM, n0 = blockIdx.y * BN;

  f32x4 acc[4][4] = {};

  // stage mapping: idx in [0,512): row-pair rp=idx>>3, phys seg sp=idx&7,
  // logical sl = sp ^ (rp&7) -> row = rp*2 + (sl>>2), col = (sl&3)*8
  int srow[2], scol[2];
#pragma unroll
  for (int i = 0; i < 2; i++) {
    const int idx = i * 256 + tid;
    const int rp = idx >> 3, sp = idx & 7, sl = sp ^ (rp & 7);
    srow[i] = rp * 2 + (sl >> 2);
    scol[i] = (sl & 3) * 8;
  }

#define QKV_STAGE(bu, k0)                                                        \
  {                                                                              \
    _Pragma("unroll") for (int i = 0; i < 2; i++) {                              \
      const int idx = i * 256 + tid;                                             \
      gload_lds16(A + (size_t)(m0 + srow[i]) * K + (k0) + scol[i],               \
                  (char*)&As[bu][0] + idx * 16);                                 \
      gload_lds16(Bt + (size_t)(n0 + srow[i]) * K + (k0) + scol[i],              \
                  (char*)&Bs[bu][0] + idx * 16);                                 \
    }                                                                            \
  }

  QKV_STAGE(0, 0);
  asm volatile("s_waitcnt vmcnt(0)" ::: "memory");
  __syncthreads();

  int bu = 0;
  for (int k0 = 0; k0 < K; k0 += BK) {
    if (k0 + BK < K) QKV_STAGE(bu ^ 1, k0 + BK);

    bf16x8 af[4], bfr[4];
    const int sp = ((l15 & 1) * 4 + l4) ^ (l15 >> 1);
#pragma unroll
    for (int mt = 0; mt < 4; mt++)
      af[mt] = *(const bf16x8*)&As[bu][(wm * 32 + mt * 8 + (l15 >> 1)) * 64 + sp * 8];
#pragma unroll
    for (int nt = 0; nt < 4; nt++)
      bfr[nt] = *(const bf16x8*)&Bs[bu][(wn * 32 + nt * 8 + (l15 >> 1)) * 64 + sp * 8];
    __builtin_amdgcn_s_setprio(1);
#pragma unroll
    for (int mt = 0; mt < 4; mt++)
#pragma unroll
      for (int nt = 0; nt < 4; nt++)
        acc[mt][nt] = __builtin_amdgcn_mfma_f32_16x16x32_bf16(af[mt], bfr[nt], acc[mt][nt], 0, 0, 0);
    __builtin_amdgcn_s_setprio(0);

    asm volatile("s_waitcnt vmcnt(0)" ::: "memory");
    __syncthreads();
    bu ^= 1;
  }

  const int region = n0 / 3072;  // block-uniform
  const float* bias = region == 0 ? bq : (region == 1 ? bk : bv);
  const float kQScale = 0.09016844f;  // (1/16) * log2(e)
#pragma unroll
  for (int nt = 0; nt < 4; nt++) {
    const int n = n0 + wn * 64 + nt * 16 + l15;
    const int col = n - region * 3072;
    const float bvv = bias[col];
#pragma unroll
    for (int mt = 0; mt < 4; mt++) {
      const int mrow = m0 + wm * 64 + mt * 16 + 4 * l4;
      f32x4 v = acc[mt][nt];
      if (region == 0) {
#pragma unroll
        for (int r = 0; r < 4; r++)
          qout[(size_t)(mrow + r) * EH + col] = f2bf((v[r] + bvv) * kQScale);
      } else if (region == 1) {
#pragma unroll
        for (int r = 0; r < 4; r++)
          kout[(size_t)(mrow + r) * EH + col] = f2bf(v[r] + bvv);
      } else {
        const int bb = mrow >> 10;
        const int s  = mrow & 1023;
        const int h  = col >> 8, d = col & 255;
        short4v o4;
        o4[0] = f2bf(v[0] + bvv); o4[1] = f2bf(v[1] + bvv);
        o4[2] = f2bf(v[2] + bvv); o4[3] = f2bf(v[3] + bvv);
        *(short4v*)&vout[((size_t)(bb * NH + h) * EMB + d) * SEQ + s] = o4;
      }
    }
  }
#undef QKV_STAGE
}

// ------- fc GEMM: out = ctx * WfcT^T + bias (fp32). BM=BN=64, BK=64, dbuf ----
// 128B rows, seg ^= row&7 -> conflict-free.
__global__ __launch_bounds__(256) void fc_gemm_kernel(const short* __restrict__ A,
                                                      const short* __restrict__ Bt,
                                                      const float* __restrict__ bias,
                                                      float* __restrict__ Cout,
                                                      int M, int N, int K) {
  constexpr int BM = 64, BN = 64, BK = 64;
  __shared__ short As[2][BM * BK];
  __shared__ short Bs[2][BN * BK];
  const int tid = threadIdx.x;
  const int w = tid >> 6, lane = tid & 63;
  const int wm = w >> 1, wn = w & 1;
  const int l15 = lane & 15, l4 = lane >> 4;
  const int m0 = blockIdx.x * BM, n0 = blockIdx.y * BN;

  f32x4 acc[2][2] = {};

  int srow[2], scol[2];
#pragma unroll
  for (int i = 0; i < 2; i++) {
    const int idx = i * 256 + tid;
    const int row = idx >> 3, sp = idx & 7, sl = sp ^ (row & 7);
    srow[i] = row;
    scol[i] = sl * 8;
  }

#define FC_STAGE(bu, k0)                                                         \
  {                                                                              \
    _Pragma("unroll") for (int i = 0; i < 2; i++) {                              \
      const int idx = i * 256 + tid;                                             \
      gload_lds16(A + (size_t)(m0 + srow[i]) * K + (k0) + scol[i],               \
                  (char*)&As[bu][0] + idx * 16);                                 \
      gload_lds16(Bt + (size_t)(n0 + srow[i]) * K + (k0) + scol[i],              \
                  (char*)&Bs[bu][0] + idx * 16);                                 \
    }                                                                            \
  }

  FC_STAGE(0, 0);
  asm volatile("s_waitcnt vmcnt(0)" ::: "memory");
  __syncthreads();

  int bu = 0;
  for (int k0 = 0; k0 < K; k0 += BK) {
    if (k0 + BK < K) FC_STAGE(bu ^ 1, k0 + BK);

    bf16x8 af[2][2], bfr[2][2];
#pragma unroll
    for (int kst = 0; kst < 2; kst++) {
      const int sp = (kst * 4 + l4) ^ (l15 & 7);
#pragma unroll
      for (int mt = 0; mt < 2; mt++)
        af[mt][kst] = *(const bf16x8*)&As[bu][(wm * 32 + mt * 16 + l15) * 64 + sp * 8];
#pragma unroll
      for (int nt = 0; nt < 2; nt++)
        bfr[nt][kst] = *(const bf16x8*)&Bs[bu][(wn * 32 + nt * 16 + l15) * 64 + sp * 8];
    }
    __builtin_amdgcn_s_setprio(1);
#pragma unroll
    for (int kst = 0; kst < 2; kst++)
#pragma unroll
      for (int mt = 0; mt < 2; mt++)
#pragma unroll
        for (int nt = 0; nt < 2; nt++)
          acc[mt][nt] = __builtin_amdgcn_mfma_f32_16x16x32_bf16(af[mt][kst], bfr[nt][kst], acc[mt][nt], 0, 0, 0);
    __builtin_amdgcn_s_setprio(0);

    asm volatile("s_waitcnt vmcnt(0)" ::: "memory");
    __syncthreads();
    bu ^= 1;
  }

#pragma unroll
  for (int nt = 0; nt < 2; nt++) {
    const int n = n0 + wn * 32 + nt * 16 + l15;
    const float bvv = bias[n];
#pragma unroll
    for (int mt = 0; mt < 2; mt++) {
      const int mrow = m0 + wm * 32 + mt * 16 + 4 * l4;
      f32x4 v = acc[mt][nt];
#pragma unroll
      for (int r = 0; r < 4; r++)
        Cout[(size_t)(mrow + r) * N + n] = v[r] + bvv;
    }
  }
#undef FC_STAGE
}

// ---------------- causal flash attention (8-wave, dbuf K+V, swizzled) --------
// grid (48, 8), qt = 7 - blockIdx.y (heavy-first). 512 threads = 8 waves x 16
// q-rows -> QBLK=128. KVBLK=32. LDS 72KB: Ks/Vs double-buffered (128B-row,
// XOR-seg, conflict-free reads; pre-swizzled gload_lds SOURCE per G21) + Ps.
// One vmcnt(0)+barrier per tile; stage issued before compute (T3 2-phase).
// Q pre-scaled log2e/16; exp2-domain softmax, defer-rescale, distributed l,
// diagonal-only masking, fully-masked waves skip compute.
__global__ __launch_bounds__(512) void attn_kernel(const short* __restrict__ Q,
                                                   const short* __restrict__ Kg,
                                                   const short* __restrict__ Vt,
                                                   short* __restrict__ Ctx) {
  __shared__ short Ks[2][8192];   // [4 kstp][32 kv][8 seg of 16B]
  __shared__ short Vs[2][8192];   // [128 dp][8 seg of 16B]
  __shared__ short Ps[8][512];    // per-wave [16 q][32 kv], seg-swizzled
  const int tid = threadIdx.x, w = tid >> 6, lane = tid & 63;
  const int l15 = lane & 15, l4 = lane >> 4;
  const int bh = blockIdx.x, b = bh / NH, h = bh % NH;
  const int qt = (gridDim.y - 1) - blockIdx.y;   // heavy-first
  const int q0 = qt * 128;
  const int qw0 = q0 + w * 16;
  const int ntiles = 4 * qt + 4;

  const float kMaskL2 = -14426.95f;   // -10000 * log2(e)
  const float kThrL2  = 11.5f;        // ~8 nats defer threshold

  const short* Kbase = Kg + (size_t)b * SEQ * EH + h * EMB;
  const short* Vbase = Vt + (size_t)bh * EMB * SEQ;

  // stage source offsets (tile-invariant part), 2 K + 2 V chunks per thread
  int koff[2], voff[2];
#pragma unroll
  for (int i = 0; i < 2; i++) {
    const int idx = i * 512 + tid;     // [0, 1024)
    {
      const int kv = (idx >> 3) & 31, sp = idx & 7, sl = sp ^ (kv & 7);
      koff[i] = kv * EH + (idx >> 8) * 64 + sl * 8;
    }
    {
      const int dp = idx >> 3, sp = idx & 7, sl = sp ^ (dp & 7);
      voff[i] = (dp * 2 + (sl >> 2)) * SEQ + (sl & 3) * 8;
    }
  }

  bf16x8 qf[8];
  {
    const short* qp = Q + (size_t)(b * SEQ + qw0 + l15) * EH + h * EMB + 8 * l4;
#pragma unroll
    for (int kst = 0; kst < 8; kst++) qf[kst] = *(const bf16x8*)(qp + 32 * kst);
  }

  // prologue: stage tile 0 -> buf 0
#pragma unroll
  for (int i = 0; i < 2; i++) {
    const int idx = i * 512 + tid;
    gload_lds16(Kbase + koff[i], (char*)&Ks[0][0] + idx * 16);
    gload_lds16(Vbase + voff[i], (char*)&Vs[0][0] + idx * 16);
  }
  asm volatile("s_waitcnt vmcnt(0)" ::: "memory");
  __syncthreads();

  f32x4 o[16] = {};
  float mst[4], lst[4];
#pragma unroll
  for (int r = 0; r < 4; r++) { mst[r] = -1e30f; lst[r] = 0.f; }

  int bu = 0;
  for (int t = 0; t < ntiles; t++) {
    const int kv0 = t * 32;

    // ---- issue next-tile stage into buf^1 (hides under compute) ----
    if (t + 1 < ntiles) {
      const short* kp = Kbase + (size_t)(kv0 + 32) * EH;
      const short* vp = Vbase + kv0 + 32;
#pragma unroll
      for (int i = 0; i < 2; i++) {
        const int idx = i * 512 + tid;
        gload_lds16(kp + koff[i], (char*)&Ks[bu ^ 1][0] + idx * 16);
        gload_lds16(vp + voff[i], (char*)&Vs[bu ^ 1][0] + idx * 16);
      }
    }

    if (kv0 <= qw0 + 15) {   // wave-uniform: skip fully-masked tiles
      // ---- S = Q K^T ----
      f32x4 sf[2] = {};
      __builtin_amdgcn_s_setprio(1);
#pragma unroll
      for (int nt = 0; nt < 2; nt++)
#pragma unroll
        for (int kst = 0; kst < 8; kst++) {
          const int sp = (((kst & 1) << 2) + l4) ^ (l15 & 7);
          bf16x8 kf = *(const bf16x8*)&Ks[bu][(kst >> 1) * 2048 + (nt * 16 + l15) * 64 + sp * 8];
          sf[nt] = __builtin_amdgcn_mfma_f32_16x16x32_bf16(qf[kst], kf, sf[nt], 0, 0, 0);
        }
      __builtin_amdgcn_s_setprio(0);

      // ---- online softmax (exp2 domain, defer-rescale, distributed l) ----
      const bool maskt = (kv0 + 31 > qw0);
      float pp[2][4];
      float fsc[4];
      bool skip[4];
#pragma unroll
      for (int r = 0; r < 4; r++) {
        float sc[2];
        float mx = -1e30f;
#pragma unroll
        for (int nt = 0; nt < 2; nt++) {
          float s = sf[nt][r];
          if (maskt) {
            const int qrow = qw0 + 4 * l4 + r;
            s += (kv0 + nt * 16 + l15 > qrow) ? kMaskL2 : 0.0f;
          }
          sc[nt] = s;
          mx = fmaxf(mx, s);
        }
        mx = fmaxf(mx, __shfl_xor(mx, 1));
        mx = fmaxf(mx, __shfl_xor(mx, 2));
        mx = fmaxf(mx, __shfl_xor(mx, 4));
        mx = fmaxf(mx, __shfl_xor(mx, 8));
        skip[r] = __all(mx <= mst[r] + kThrL2);
        float mref;
        if (skip[r]) {
          fsc[r] = 1.0f;
          mref = mst[r];
        } else {
          float mnew = fmaxf(mst[r], mx);
          fsc[r] = exp2f(mst[r] - mnew);
          mst[r] = mnew;
          mref = mnew;
        }
        float rs = 0.f;
#pragma unroll
        for (int nt = 0; nt < 2; nt++) {
          float e = exp2f(sc[nt] - mref);
          pp[nt][r] = e;
          rs += e;
        }
        lst[r] = lst[r] * fsc[r] + rs;
      }
#pragma unroll
      for (int r = 0; r < 4; r++) {
        if (!skip[r]) {
#pragma unroll
          for (int nt = 0; nt < 16; nt++) o[nt][r] *= fsc[r];
        }
      }

      // ---- P -> per-wave LDS, seg-swizzled (2-way = free) ----
#pragma unroll
      for (int nt = 0; nt < 2; nt++)
#pragma unroll
        for (int r = 0; r < 4; r++) {
          const int prow = 4 * l4 + r;
          const int col  = nt * 16 + l15;
          const int pseg = (col >> 3) ^ ((prow >> 1) & 3);
          Ps[w][prow * 32 + pseg * 8 + (col & 7)] = f2bf(pp[nt][r]);
        }

      // ---- O += P V (V from LDS, conflict-free) ----
      const int aseg = l4 ^ ((l15 >> 1) & 3);
      bf16x8 af = *(const bf16x8*)&Ps[w][l15 * 32 + aseg * 8];
      const int vsp = ((l15 & 1) * 4 + l4) ^ (l15 >> 1);
      __builtin_amdgcn_s_setprio(1);
#pragma unroll
      for (int nt = 0; nt < 16; nt++) {
        const int dp = nt * 8 + (l15 >> 1);
        bf16x8 vf = *(const bf16x8*)&Vs[bu][dp * 64 + vsp * 8];
        o[nt] = __builtin_amdgcn_mfma_f32_16x16x32_bf16(af, vf, o[nt], 0, 0, 0);
      }
      __builtin_amdgcn_s_setprio(0);
    }

    // ---- single per-tile sync: next stage complete + all reads done ----
    asm volatile("s_waitcnt vmcnt(0)" ::: "memory");
    __syncthreads();
    bu ^= 1;
  }

  // ---- reduce distributed l, normalize, store ctx ----
  float inv[4];
#pragma unroll
  for (int r = 0; r < 4; r++) {
    float rs = lst[r];
    rs += __shfl_xor(rs, 1);
    rs += __shfl_xor(rs, 2);
    rs += __shfl_xor(rs, 4);
    rs += __shfl_xor(rs, 8);
    inv[r] = 1.f / rs;
  }
  const int mrow = b * SEQ + qw0 + 4 * l4;
#pragma unroll
  for (int nt = 0; nt < 16; nt++) {
    const int d = h * EMB + nt * 16 + l15;
#pragma unroll
    for (int r = 0; r < 4; r++)
      Ctx[(size_t)(mrow + r) * EH + d] = f2bf(o[nt][r] * inv[r]);
  }
}

extern "C" void kernel_launch(void* const* d_in, const int* in_sizes, int n_in,
                              void* d_out, int out_size, void* d_ws, size_t ws_size,
                              hipStream_t stream) {
  const float* x   = (const float*)d_in[0];
  const float* Wq  = (const float*)d_in[2];
  const float* bq  = (const float*)d_in[3];
  const float* Wk  = (const float*)d_in[4];
  const float* bk  = (const float*)d_in[5];
  const float* Wv  = (const float*)d_in[6];
  const float* bv  = (const float*)d_in[7];
  const float* Wfc = (const float*)d_in[8];
  const float* bfc = (const float*)d_in[9];
  float* out = (float*)d_out;

  short* ws    = (short*)d_ws;
  short* xb    = ws;                  // 4096*256
  short* wqkvt = xb + 1048576;        // 3*3072*256 contiguous [9216][256]
  short* wfct  = wqkvt + 3 * 786432;  // 256*3072
  short* q     = wfct + 786432;       // 4096*3072 (pre-scaled by log2e/16)
  short* k     = q + 12582912;
  short* vt    = k + 12582912;        // [b][h][d][s]
  short* ctx   = vt + 12582912;       // 4096*3072

  cast_x_kernel<<<1024, 256, 0, stream>>>(x, xb);
  transpose_qkv_kernel<<<dim3(EH / 32, EMB / 32, 3), 256, 0, stream>>>(Wq, Wk, Wv, wqkvt);
  transpose_cast_kernel<<<dim3(EMB / 32, EH / 32), 256, 0, stream>>>(Wfc, wfct, EH, EMB);

  qkv_gemm_kernel<<<dim3(MROWS / 128, 9216 / 128), 256, 0, stream>>>(
      xb, wqkvt, bq, bk, bv, q, k, vt);

  attn_kernel<<<dim3(BATCH * NH, SEQ / 128), 512, 0, stream>>>(q, k, vt, ctx);

  fc_gemm_kernel<<<dim3(MROWS / 64, EMB / 64), 256, 0, stream>>>(ctx, wfct, bfc, out, MROWS, EMB, EH);
}

// Round 9
// 160.376 us; speedup vs baseline: 1.6855x; 1.1165x over previous
//
#include <hip/hip_runtime.h>

#define BATCH 4
#define SEQ   1024
#define EMB   256
#define NH    12
#define EH    3072   // EMB*NH
#define MROWS 4096   // BATCH*SEQ

typedef __attribute__((ext_vector_type(8))) short bf16x8;
typedef __attribute__((ext_vector_type(4))) float f32x4;
typedef __attribute__((ext_vector_type(4))) short short4v;

__device__ __forceinline__ short f2bf(float f) {
  union { float f; unsigned u; } x; x.f = f;
  unsigned r = x.u + 0x7fffu + ((x.u >> 16) & 1u);  // round-to-nearest-even
  return (short)(r >> 16);
}

__device__ __forceinline__ void gload_lds16(const void* g, void* l) {
  __builtin_amdgcn_global_load_lds(
      (const __attribute__((address_space(1))) unsigned*)g,
      (__attribute__((address_space(3))) unsigned*)l, 16, 0, 0);
}

// ---------------- cast x (fp32 -> bf16) ----------------
__global__ __launch_bounds__(256) void cast_x_kernel(const float* __restrict__ in,
                                                     short* __restrict__ out) {
  int i = (blockIdx.x * 256 + threadIdx.x) * 4;
  float4 v = *(const float4*)(in + i);
  short4v o;
  o[0] = f2bf(v.x); o[1] = f2bf(v.y); o[2] = f2bf(v.z); o[3] = f2bf(v.w);
  *(short4v*)(out + i) = o;
}

// ------- transpose + cast, fused QKV: z selects Wq/Wk/Wv (all [EMB][EH]) -------
__global__ __launch_bounds__(256) void transpose_qkv_kernel(const float* __restrict__ Wq,
                                                            const float* __restrict__ Wk,
                                                            const float* __restrict__ Wv,
                                                            short* __restrict__ Wt) {
  __shared__ float tile[32][33];
  const float* W = blockIdx.z == 0 ? Wq : (blockIdx.z == 1 ? Wk : Wv);
  short* o = Wt + (size_t)blockIdx.z * EH * EMB;
  const int n0 = blockIdx.x * 32, k0 = blockIdx.y * 32;
  const int tx = threadIdx.x & 31, ty = threadIdx.x >> 5;  // 32 x 8
#pragma unroll
  for (int i = 0; i < 4; i++)
    tile[ty + 8 * i][tx] = W[(size_t)(k0 + ty + 8 * i) * EH + n0 + tx];
  __syncthreads();
#pragma unroll
  for (int i = 0; i < 4; i++) {
    int nr = ty + 8 * i;
    o[(size_t)(n0 + nr) * EMB + k0 + tx] = f2bf(tile[tx][nr]);
  }
}

// ---------------- generic transpose + cast W[K][N] -> Wt[N][K] ----------------
__global__ __launch_bounds__(256) void transpose_cast_kernel(const float* __restrict__ W,
                                                             short* __restrict__ Wt,
                                                             int K, int N) {
  __shared__ float tile[32][33];
  const int n0 = blockIdx.x * 32, k0 = blockIdx.y * 32;
  const int tx = threadIdx.x & 31, ty = threadIdx.x >> 5;
#pragma unroll
  for (int i = 0; i < 4; i++)
    tile[ty + 8 * i][tx] = W[(size_t)(k0 + ty + 8 * i) * N + n0 + tx];
  __syncthreads();
#pragma unroll
  for (int i = 0; i < 4; i++) {
    int nr = ty + 8 * i;
    Wt[(size_t)(n0 + nr) * K + k0 + tx] = f2bf(tile[tx][nr]);
  }
}

// ------- fused QKV GEMM: C[4096][9216] = xb * WqkvT^T, region epilogues -------
// BM=BN=128, BK=32, DOUBLE-BUFFERED (T3 2-phase), row-pair XOR-swizzled LDS
// (conflict-free ds_read_b128). region 0: q (pre-scaled log2e/16); 1: k;
// 2: v -> [b][h][d][s].
__global__ __launch_bounds__(256) void qkv_gemm_kernel(const short* __restrict__ A,
                                                       const short* __restrict__ Bt,
                                                       const float* __restrict__ bq,
                                                       const float* __restrict__ bk,
                                                       const float* __restrict__ bv,
                                                       short* __restrict__ qout,
                                                       short* __restrict__ kout,
                                                       short* __restrict__ vout) {
  constexpr int BM = 128, BN = 128, BK = 32, K = EMB;
  __shared__ short As[2][BM * BK];
  __shared__ short Bs[2][BN * BK];
  const int tid = threadIdx.x;
  const int w = tid >> 6, lane = tid & 63;
  const int wm = w >> 1, wn = w & 1;
  const int l15 = lane & 15, l4 = lane >> 4;
  const int m0 = blockIdx.x * BM, n0 = blockIdx.y * BN;

  f32x4 acc[4][4] = {};

  int srow[2], scol[2];
#pragma unroll
  for (int i = 0; i < 2; i++) {
    const int idx = i * 256 + tid;
    const int rp = idx >> 3, sp = idx & 7, sl = sp ^ (rp & 7);
    srow[i] = rp * 2 + (sl >> 2);
    scol[i] = (sl & 3) * 8;
  }

#define QKV_STAGE(bu, k0)                                                        \
  {                                                                              \
    _Pragma("unroll") for (int i = 0; i < 2; i++) {                              \
      const int idx = i * 256 + tid;                                             \
      gload_lds16(A + (size_t)(m0 + srow[i]) * K + (k0) + scol[i],               \
                  (char*)&As[bu][0] + idx * 16);                                 \
      gload_lds16(Bt + (size_t)(n0 + srow[i]) * K + (k0) + scol[i],              \
                  (char*)&Bs[bu][0] + idx * 16);                                 \
    }                                                                            \
  }

  QKV_STAGE(0, 0);
  asm volatile("s_waitcnt vmcnt(0)" ::: "memory");
  __syncthreads();

  int bu = 0;
  for (int k0 = 0; k0 < K; k0 += BK) {
    if (k0 + BK < K) QKV_STAGE(bu ^ 1, k0 + BK);

    bf16x8 af[4], bfr[4];
    const int sp = ((l15 & 1) * 4 + l4) ^ (l15 >> 1);
#pragma unroll
    for (int mt = 0; mt < 4; mt++)
      af[mt] = *(const bf16x8*)&As[bu][(wm * 32 + mt * 8 + (l15 >> 1)) * 64 + sp * 8];
#pragma unroll
    for (int nt = 0; nt < 4; nt++)
      bfr[nt] = *(const bf16x8*)&Bs[bu][(wn * 32 + nt * 8 + (l15 >> 1)) * 64 + sp * 8];
    __builtin_amdgcn_s_setprio(1);
#pragma unroll
    for (int mt = 0; mt < 4; mt++)
#pragma unroll
      for (int nt = 0; nt < 4; nt++)
        acc[mt][nt] = __builtin_amdgcn_mfma_f32_16x16x32_bf16(af[mt], bfr[nt], acc[mt][nt], 0, 0, 0);
    __builtin_amdgcn_s_setprio(0);

    asm volatile("s_waitcnt vmcnt(0)" ::: "memory");
    __syncthreads();
    bu ^= 1;
  }

  const int region = n0 / 3072;  // block-uniform
  const float* bias = region == 0 ? bq : (region == 1 ? bk : bv);
  const float kQScale = 0.09016844f;  // (1/16) * log2(e)
#pragma unroll
  for (int nt = 0; nt < 4; nt++) {
    const int n = n0 + wn * 64 + nt * 16 + l15;
    const int col = n - region * 3072;
    const float bvv = bias[col];
#pragma unroll
    for (int mt = 0; mt < 4; mt++) {
      const int mrow = m0 + wm * 64 + mt * 16 + 4 * l4;
      f32x4 v = acc[mt][nt];
      if (region == 0) {
#pragma unroll
        for (int r = 0; r < 4; r++)
          qout[(size_t)(mrow + r) * EH + col] = f2bf((v[r] + bvv) * kQScale);
      } else if (region == 1) {
#pragma unroll
        for (int r = 0; r < 4; r++)
          kout[(size_t)(mrow + r) * EH + col] = f2bf(v[r] + bvv);
      } else {
        const int bb = mrow >> 10;
        const int s  = mrow & 1023;
        const int h  = col >> 8, d = col & 255;
        short4v o4;
        o4[0] = f2bf(v[0] + bvv); o4[1] = f2bf(v[1] + bvv);
        o4[2] = f2bf(v[2] + bvv); o4[3] = f2bf(v[3] + bvv);
        *(short4v*)&vout[((size_t)(bb * NH + h) * EMB + d) * SEQ + s] = o4;
      }
    }
  }
#undef QKV_STAGE
}

// ------- fc GEMM: out = ctx * WfcT^T + bias (fp32). BM=BN=64, BK=64, dbuf ----
__global__ __launch_bounds__(256) void fc_gemm_kernel(const short* __restrict__ A,
                                                      const short* __restrict__ Bt,
                                                      const float* __restrict__ bias,
                                                      float* __restrict__ Cout,
                                                      int M, int N, int K) {
  constexpr int BM = 64, BN = 64, BK = 64;
  __shared__ short As[2][BM * BK];
  __shared__ short Bs[2][BN * BK];
  const int tid = threadIdx.x;
  const int w = tid >> 6, lane = tid & 63;
  const int wm = w >> 1, wn = w & 1;
  const int l15 = lane & 15, l4 = lane >> 4;
  const int m0 = blockIdx.x * BM, n0 = blockIdx.y * BN;

  f32x4 acc[2][2] = {};

  int srow[2], scol[2];
#pragma unroll
  for (int i = 0; i < 2; i++) {
    const int idx = i * 256 + tid;
    const int row = idx >> 3, sp = idx & 7, sl = sp ^ (row & 7);
    srow[i] = row;
    scol[i] = sl * 8;
  }

#define FC_STAGE(bu, k0)                                                         \
  {                                                                              \
    _Pragma("unroll") for (int i = 0; i < 2; i++) {                              \
      const int idx = i * 256 + tid;                                             \
      gload_lds16(A + (size_t)(m0 + srow[i]) * K + (k0) + scol[i],               \
                  (char*)&As[bu][0] + idx * 16);                                 \
      gload_lds16(Bt + (size_t)(n0 + srow[i]) * K + (k0) + scol[i],              \
                  (char*)&Bs[bu][0] + idx * 16);                                 \
    }                                                                            \
  }

  FC_STAGE(0, 0);
  asm volatile("s_waitcnt vmcnt(0)" ::: "memory");
  __syncthreads();

  int bu = 0;
  for (int k0 = 0; k0 < K; k0 += BK) {
    if (k0 + BK < K) FC_STAGE(bu ^ 1, k0 + BK);

    bf16x8 af[2][2], bfr[2][2];
#pragma unroll
    for (int kst = 0; kst < 2; kst++) {
      const int sp = (kst * 4 + l4) ^ (l15 & 7);
#pragma unroll
      for (int mt = 0; mt < 2; mt++)
        af[mt][kst] = *(const bf16x8*)&As[bu][(wm * 32 + mt * 16 + l15) * 64 + sp * 8];
#pragma unroll
      for (int nt = 0; nt < 2; nt++)
        bfr[nt][kst] = *(const bf16x8*)&Bs[bu][(wn * 32 + nt * 16 + l15) * 64 + sp * 8];
    }
    __builtin_amdgcn_s_setprio(1);
#pragma unroll
    for (int kst = 0; kst < 2; kst++)
#pragma unroll
      for (int mt = 0; mt < 2; mt++)
#pragma unroll
        for (int nt = 0; nt < 2; nt++)
          acc[mt][nt] = __builtin_amdgcn_mfma_f32_16x16x32_bf16(af[mt][kst], bfr[nt][kst], acc[mt][nt], 0, 0, 0);
    __builtin_amdgcn_s_setprio(0);

    asm volatile("s_waitcnt vmcnt(0)" ::: "memory");
    __syncthreads();
    bu ^= 1;
  }

#pragma unroll
  for (int nt = 0; nt < 2; nt++) {
    const int n = n0 + wn * 32 + nt * 16 + l15;
    const float bvv = bias[n];
#pragma unroll
    for (int mt = 0; mt < 2; mt++) {
      const int mrow = m0 + wm * 32 + mt * 16 + 4 * l4;
      f32x4 v = acc[mt][nt];
#pragma unroll
      for (int r = 0; r < 4; r++)
        Cout[(size_t)(mrow + r) * N + n] = v[r] + bvv;
    }
  }
#undef FC_STAGE
}

// ---------------- causal flash attention (swapped QK^T softmax) --------------
// grid (48, 8), qt = 7 - blockIdx.y (heavy-first). 8 waves x 16 q-rows,
// KVBLK=32, dbuf K+V via pre-swizzled gload_lds (R8-verified, 0 conflicts).
// T12 swapped QK: S = mfma(K, Q) puts each q-row's scores in a 4-lane group
// -> row reduce = 7 in-lane fmax + 2 shfl_xor (was 16 shfl); m/l state are
// per-lane scalars; fsc/inv broadcast to O rows via 4 bpermutes (rare/final).
__global__ __launch_bounds__(512) void attn_kernel(const short* __restrict__ Q,
                                                   const short* __restrict__ Kg,
                                                   const short* __restrict__ Vt,
                                                   short* __restrict__ Ctx) {
  __shared__ short Ks[2][8192];   // [4 kstp][32 kv][8 seg of 16B]
  __shared__ short Vs[2][8192];   // [128 dp][8 seg of 16B]
  __shared__ short Ps[8][512];    // per-wave [16 q][32 kv], seg-swizzled
  const int tid = threadIdx.x, w = tid >> 6, lane = tid & 63;
  const int l15 = lane & 15, l4 = lane >> 4;
  const int bh = blockIdx.x, b = bh / NH, h = bh % NH;
  const int qt = (gridDim.y - 1) - blockIdx.y;   // heavy-first
  const int q0 = qt * 128;
  const int qw0 = q0 + w * 16;
  const int ntiles = 4 * qt + 4;

  const float kMaskL2 = -14426.95f;   // -10000 * log2(e)
  const float kThrL2  = 11.5f;        // ~8 nats defer threshold

  const short* Kbase = Kg + (size_t)b * SEQ * EH + h * EMB;
  const short* Vbase = Vt + (size_t)bh * EMB * SEQ;

  int koff[2], voff[2];
#pragma unroll
  for (int i = 0; i < 2; i++) {
    const int idx = i * 512 + tid;     // [0, 1024)
    {
      const int kv = (idx >> 3) & 31, sp = idx & 7, sl = sp ^ (kv & 7);
      koff[i] = kv * EH + (idx >> 8) * 64 + sl * 8;
    }
    {
      const int dp = idx >> 3, sp = idx & 7, sl = sp ^ (dp & 7);
      voff[i] = (dp * 2 + (sl >> 2)) * SEQ + (sl & 3) * 8;
    }
  }

  bf16x8 qf[8];
  {
    const short* qp = Q + (size_t)(b * SEQ + qw0 + l15) * EH + h * EMB + 8 * l4;
#pragma unroll
    for (int kst = 0; kst < 8; kst++) qf[kst] = *(const bf16x8*)(qp + 32 * kst);
  }

  // prologue: stage tile 0 -> buf 0
#pragma unroll
  for (int i = 0; i < 2; i++) {
    const int idx = i * 512 + tid;
    gload_lds16(Kbase + koff[i], (char*)&Ks[0][0] + idx * 16);
    gload_lds16(Vbase + voff[i], (char*)&Vs[0][0] + idx * 16);
  }
  asm volatile("s_waitcnt vmcnt(0)" ::: "memory");
  __syncthreads();

  f32x4 o[16] = {};
  float mst = -1e30f, lst = 0.f;   // per-lane scalars (q = qw0 + l15)

  int bu = 0;
  for (int t = 0; t < ntiles; t++) {
    const int kv0 = t * 32;

    // ---- issue next-tile stage into buf^1 (hides under compute) ----
    if (t + 1 < ntiles) {
      const short* kp = Kbase + (size_t)(kv0 + 32) * EH;
      const short* vp = Vbase + kv0 + 32;
#pragma unroll
      for (int i = 0; i < 2; i++) {
        const int idx = i * 512 + tid;
        gload_lds16(kp + koff[i], (char*)&Ks[bu ^ 1][0] + idx * 16);
        gload_lds16(vp + voff[i], (char*)&Vs[bu ^ 1][0] + idx * 16);
      }
    }

    if (kv0 <= qw0 + 15) {   // wave-uniform: skip fully-masked tiles
      // ---- S = K Q^T (swapped): row=kv=4*l4+r, col=q=l15 ----
      f32x4 sf[2] = {};
      __builtin_amdgcn_s_setprio(1);
#pragma unroll
      for (int nt = 0; nt < 2; nt++)
#pragma unroll
        for (int kst = 0; kst < 8; kst++) {
          const int sp = (((kst & 1) << 2) + l4) ^ (l15 & 7);
          bf16x8 kf = *(const bf16x8*)&Ks[bu][(kst >> 1) * 2048 + (nt * 16 + l15) * 64 + sp * 8];
          sf[nt] = __builtin_amdgcn_mfma_f32_16x16x32_bf16(kf, qf[kst], sf[nt], 0, 0, 0);
        }
      __builtin_amdgcn_s_setprio(0);

      // ---- online softmax: per-lane scalar state, 2-shfl reduce ----
      const bool maskt = (kv0 + 31 > qw0);
      float sval[2][4];
      float mxl = -1e30f;
#pragma unroll
      for (int nt = 0; nt < 2; nt++)
#pragma unroll
        for (int r = 0; r < 4; r++) {
          float s = sf[nt][r];
          if (maskt) {
            const int kv = kv0 + nt * 16 + 4 * l4 + r;
            s += (kv > qw0 + l15) ? kMaskL2 : 0.0f;
          }
          sval[nt][r] = s;
          mxl = fmaxf(mxl, s);
        }
      float mx = fmaxf(mxl, __shfl_xor(mxl, 16));
      mx = fmaxf(mx, __shfl_xor(mx, 32));
      const bool skipt = __all(mx <= mst + kThrL2);
      float mref, fsc;
      if (skipt) {
        fsc = 1.0f;
        mref = mst;
      } else {
        float mnew = fmaxf(mst, mx);
        fsc = exp2f(mst - mnew);
        mst = mnew;
        mref = mnew;
      }
      float pp[2][4];
      float lsum = 0.f;
#pragma unroll
      for (int nt = 0; nt < 2; nt++)
#pragma unroll
        for (int r = 0; r < 4; r++) {
          float e = exp2f(sval[nt][r] - mref);
          pp[nt][r] = e;
          lsum += e;
        }
      lst = lst * fsc + lsum;   // partial over this lane's 8 kv; reduced at end

      if (!skipt) {
        // broadcast fsc of o-row (4*l4+r) from its l15-owner lane
        float fv[4];
#pragma unroll
        for (int r = 0; r < 4; r++)
          fv[r] = __shfl(fsc, (lane & 48) + 4 * (lane >> 4) + r);
#pragma unroll
        for (int nt = 0; nt < 16; nt++) {
          o[nt][0] *= fv[0]; o[nt][1] *= fv[1];
          o[nt][2] *= fv[2]; o[nt][3] *= fv[3];
        }
      }

      // ---- P -> per-wave LDS [q=l15][kv], seg-swizzled ----
#pragma unroll
      for (int nt = 0; nt < 2; nt++)
#pragma unroll
        for (int r = 0; r < 4; r++) {
          const int col  = nt * 16 + 4 * l4 + r;
          const int pseg = (col >> 3) ^ ((l15 >> 1) & 3);
          Ps[w][l15 * 32 + pseg * 8 + (col & 7)] = f2bf(pp[nt][r]);
        }

      // ---- O += P V (V from LDS, conflict-free) ----
      const int aseg = l4 ^ ((l15 >> 1) & 3);
      bf16x8 af = *(const bf16x8*)&Ps[w][l15 * 32 + aseg * 8];
      const int vsp = ((l15 & 1) * 4 + l4) ^ (l15 >> 1);
      __builtin_amdgcn_s_setprio(1);
#pragma unroll
      for (int nt = 0; nt < 16; nt++) {
        const int dp = nt * 8 + (l15 >> 1);
        bf16x8 vf = *(const bf16x8*)&Vs[bu][dp * 64 + vsp * 8];
        o[nt] = __builtin_amdgcn_mfma_f32_16x16x32_bf16(af, vf, o[nt], 0, 0, 0);
      }
      __builtin_amdgcn_s_setprio(0);
    }

    // ---- single per-tile sync: next stage complete + all reads done ----
    asm volatile("s_waitcnt vmcnt(0)" ::: "memory");
    __syncthreads();
    bu ^= 1;
  }

  // ---- reduce distributed l (butterfly -> all lanes), broadcast inv ----
  lst += __shfl_xor(lst, 16);
  lst += __shfl_xor(lst, 32);
  const float inv = 1.f / lst;
  float invv[4];
#pragma unroll
  for (int r = 0; r < 4; r++)
    invv[r] = __shfl(inv, (lane & 48) + 4 * (lane >> 4) + r);

  const int mrow = b * SEQ + qw0 + 4 * l4;
#pragma unroll
  for (int nt = 0; nt < 16; nt++) {
    const int d = h * EMB + nt * 16 + l15;
#pragma unroll
    for (int r = 0; r < 4; r++)
      Ctx[(size_t)(mrow + r) * EH + d] = f2bf(o[nt][r] * invv[r]);
  }
}

extern "C" void kernel_launch(void* const* d_in, const int* in_sizes, int n_in,
                              void* d_out, int out_size, void* d_ws, size_t ws_size,
                              hipStream_t stream) {
  const float* x   = (const float*)d_in[0];
  const float* Wq  = (const float*)d_in[2];
  const float* bq  = (const float*)d_in[3];
  const float* Wk  = (const float*)d_in[4];
  const float* bk  = (const float*)d_in[5];
  const float* Wv  = (const float*)d_in[6];
  const float* bv  = (const float*)d_in[7];
  const float* Wfc = (const float*)d_in[8];
  const float* bfc = (const float*)d_in[9];
  float* out = (float*)d_out;

  short* ws    = (short*)d_ws;
  short* xb    = ws;                  // 4096*256
  short* wqkvt = xb + 1048576;        // 3*3072*256 contiguous [9216][256]
  short* wfct  = wqkvt + 3 * 786432;  // 256*3072
  short* q     = wfct + 786432;       // 4096*3072 (pre-scaled by log2e/16)
  short* k     = q + 12582912;
  short* vt    = k + 12582912;        // [b][h][d][s]
  short* ctx   = vt + 12582912;       // 4096*3072

  cast_x_kernel<<<1024, 256, 0, stream>>>(x, xb);
  transpose_qkv_kernel<<<dim3(EH / 32, EMB / 32, 3), 256, 0, stream>>>(Wq, Wk, Wv, wqkvt);
  transpose_cast_kernel<<<dim3(EMB / 32, EH / 32), 256, 0, stream>>>(Wfc, wfct, EH, EMB);

  qkv_gemm_kernel<<<dim3(MROWS / 128, 9216 / 128), 256, 0, stream>>>(
      xb, wqkvt, bq, bk, bv, q, k, vt);

  attn_kernel<<<dim3(BATCH * NH, SEQ / 128), 512, 0, stream>>>(q, k, vt, ctx);

  fc_gemm_kernel<<<dim3(MROWS / 64, EMB / 64), 256, 0, stream>>>(ctx, wfct, bfc, out, MROWS, EMB, EH);
}

// Round 10
// 151.043 us; speedup vs baseline: 1.7896x; 1.0618x over previous
//
#include <hip/hip_runtime.h>

#define BATCH 4
#define SEQ   1024
#define EMB   256
#define NH    12
#define EH    3072   // EMB*NH
#define MROWS 4096   // BATCH*SEQ

typedef __attribute__((ext_vector_type(8))) short bf16x8;
typedef __attribute__((ext_vector_type(4))) float f32x4;
typedef __attribute__((ext_vector_type(4))) short short4v;

__device__ __forceinline__ short f2bf(float f) {
  union { float f; unsigned u; } x; x.f = f;
  unsigned r = x.u + 0x7fffu + ((x.u >> 16) & 1u);  // round-to-nearest-even
  return (short)(r >> 16);
}

// truncating bf16 pack for P (values in [0,1]; bias ~2^-10 rel, fine for P)
__device__ __forceinline__ unsigned pack_trunc(float a, float b) {
  union { float f; unsigned u; } x, y;
  x.f = a; y.f = b;
  return (x.u >> 16) | (y.u & 0xffff0000u);
}

__device__ __forceinline__ void gload_lds16(const void* g, void* l) {
  __builtin_amdgcn_global_load_lds(
      (const __attribute__((address_space(1))) unsigned*)g,
      (__attribute__((address_space(3))) unsigned*)l, 16, 0, 0);
}

// ---------------- cast x (fp32 -> bf16) ----------------
__global__ __launch_bounds__(256) void cast_x_kernel(const float* __restrict__ in,
                                                     short* __restrict__ out) {
  int i = (blockIdx.x * 256 + threadIdx.x) * 4;
  float4 v = *(const float4*)(in + i);
  short4v o;
  o[0] = f2bf(v.x); o[1] = f2bf(v.y); o[2] = f2bf(v.z); o[3] = f2bf(v.w);
  *(short4v*)(out + i) = o;
}

// ------- transpose + cast, fused QKV: z selects Wq/Wk/Wv (all [EMB][EH]) -------
__global__ __launch_bounds__(256) void transpose_qkv_kernel(const float* __restrict__ Wq,
                                                            const float* __restrict__ Wk,
                                                            const float* __restrict__ Wv,
                                                            short* __restrict__ Wt) {
  __shared__ float tile[32][33];
  const float* W = blockIdx.z == 0 ? Wq : (blockIdx.z == 1 ? Wk : Wv);
  short* o = Wt + (size_t)blockIdx.z * EH * EMB;
  const int n0 = blockIdx.x * 32, k0 = blockIdx.y * 32;
  const int tx = threadIdx.x & 31, ty = threadIdx.x >> 5;  // 32 x 8
#pragma unroll
  for (int i = 0; i < 4; i++)
    tile[ty + 8 * i][tx] = W[(size_t)(k0 + ty + 8 * i) * EH + n0 + tx];
  __syncthreads();
#pragma unroll
  for (int i = 0; i < 4; i++) {
    int nr = ty + 8 * i;
    o[(size_t)(n0 + nr) * EMB + k0 + tx] = f2bf(tile[tx][nr]);
  }
}

// ---------------- generic transpose + cast W[K][N] -> Wt[N][K] ----------------
__global__ __launch_bounds__(256) void transpose_cast_kernel(const float* __restrict__ W,
                                                             short* __restrict__ Wt,
                                                             int K, int N) {
  __shared__ float tile[32][33];
  const int n0 = blockIdx.x * 32, k0 = blockIdx.y * 32;
  const int tx = threadIdx.x & 31, ty = threadIdx.x >> 5;
#pragma unroll
  for (int i = 0; i < 4; i++)
    tile[ty + 8 * i][tx] = W[(size_t)(k0 + ty + 8 * i) * N + n0 + tx];
  __syncthreads();
#pragma unroll
  for (int i = 0; i < 4; i++) {
    int nr = ty + 8 * i;
    Wt[(size_t)(n0 + nr) * K + k0 + tx] = f2bf(tile[tx][nr]);
  }
}

// ------- fused QKV GEMM: C[4096][9216] = xb * WqkvT^T, region epilogues -------
// BM=BN=128, BK=64 (4 K-steps), double-buffered, 128B-row XOR-seg swizzle
// (<=2-way). region 0: q (pre-scaled log2e/16); 1: k; 2: v -> [b][h][d][s].
__global__ __launch_bounds__(256) void qkv_gemm_kernel(const short* __restrict__ A,
                                                       const short* __restrict__ Bt,
                                                       const float* __restrict__ bq,
                                                       const float* __restrict__ bk,
                                                       const float* __restrict__ bv,
                                                       short* __restrict__ qout,
                                                       short* __restrict__ kout,
                                                       short* __restrict__ vout) {
  constexpr int BM = 128, BK = 64, K = EMB;
  __shared__ short As[2][BM * BK];   // 16 KB per buf
  __shared__ short Bs[2][BM * BK];
  const int tid = threadIdx.x;
  const int w = tid >> 6, lane = tid & 63;
  const int wm = w >> 1, wn = w & 1;
  const int l15 = lane & 15, l4 = lane >> 4;
  const int m0 = blockIdx.x * BM, n0 = blockIdx.y * BM;

  f32x4 acc[4][4] = {};

  // stage mapping: tile = 128 rows x 8 segs(16B); idx = row*8 + physseg
  int srow[4], scol[4];
#pragma unroll
  for (int i = 0; i < 4; i++) {
    const int idx = i * 256 + tid;
    const int row = idx >> 3, sp = idx & 7, sl = sp ^ (row & 7);
    srow[i] = row;
    scol[i] = sl * 8;
  }

#define QKV_STAGE(bu, k0)                                                        \
  {                                                                              \
    _Pragma("unroll") for (int i = 0; i < 4; i++) {                              \
      const int idx = i * 256 + tid;                                             \
      gload_lds16(A + (size_t)(m0 + srow[i]) * K + (k0) + scol[i],               \
                  (char*)&As[bu][0] + idx * 16);                                 \
      gload_lds16(Bt + (size_t)(n0 + srow[i]) * K + (k0) + scol[i],              \
                  (char*)&Bs[bu][0] + idx * 16);                                 \
    }                                                                            \
  }

  QKV_STAGE(0, 0);
  asm volatile("s_waitcnt vmcnt(0)" ::: "memory");
  __syncthreads();

  int bu = 0;
  for (int k0 = 0; k0 < K; k0 += BK) {
    if (k0 + BK < K) QKV_STAGE(bu ^ 1, k0 + BK);

#pragma unroll
    for (int kst = 0; kst < 2; kst++) {
      const int sp = (kst * 4 + l4) ^ (l15 & 7);
      bf16x8 af[4], bfr[4];
#pragma unroll
      for (int mt = 0; mt < 4; mt++)
        af[mt] = *(const bf16x8*)&As[bu][(wm * 64 + mt * 16 + l15) * 64 + sp * 8];
#pragma unroll
      for (int nt = 0; nt < 4; nt++)
        bfr[nt] = *(const bf16x8*)&Bs[bu][(wn * 64 + nt * 16 + l15) * 64 + sp * 8];
      __builtin_amdgcn_s_setprio(1);
#pragma unroll
      for (int mt = 0; mt < 4; mt++)
#pragma unroll
        for (int nt = 0; nt < 4; nt++)
          acc[mt][nt] = __builtin_amdgcn_mfma_f32_16x16x32_bf16(af[mt], bfr[nt], acc[mt][nt], 0, 0, 0);
      __builtin_amdgcn_s_setprio(0);
    }

    asm volatile("s_waitcnt vmcnt(0)" ::: "memory");
    __syncthreads();
    bu ^= 1;
  }

  const int region = n0 / 3072;  // block-uniform
  const float* bias = region == 0 ? bq : (region == 1 ? bk : bv);
  const float kQScale = 0.09016844f;  // (1/16) * log2(e)
#pragma unroll
  for (int nt = 0; nt < 4; nt++) {
    const int n = n0 + wn * 64 + nt * 16 + l15;
    const int col = n - region * 3072;
    const float bvv = bias[col];
#pragma unroll
    for (int mt = 0; mt < 4; mt++) {
      const int mrow = m0 + wm * 64 + mt * 16 + 4 * l4;
      f32x4 v = acc[mt][nt];
      if (region == 0) {
#pragma unroll
        for (int r = 0; r < 4; r++)
          qout[(size_t)(mrow + r) * EH + col] = f2bf((v[r] + bvv) * kQScale);
      } else if (region == 1) {
#pragma unroll
        for (int r = 0; r < 4; r++)
          kout[(size_t)(mrow + r) * EH + col] = f2bf(v[r] + bvv);
      } else {
        const int bb = mrow >> 10;
        const int s  = mrow & 1023;
        const int h  = col >> 8, d = col & 255;
        short4v o4;
        o4[0] = f2bf(v[0] + bvv); o4[1] = f2bf(v[1] + bvv);
        o4[2] = f2bf(v[2] + bvv); o4[3] = f2bf(v[3] + bvv);
        *(short4v*)&vout[((size_t)(bb * NH + h) * EMB + d) * SEQ + s] = o4;
      }
    }
  }
#undef QKV_STAGE
}

// ------- fc GEMM: out = ctx * WfcT^T + bias (fp32). BM=BN=64, BK=128 (24
// steps), dbuf; 256B rows, seg ^= row&15 -> <=2-way.
__global__ __launch_bounds__(256) void fc_gemm_kernel(const short* __restrict__ A,
                                                      const short* __restrict__ Bt,
                                                      const float* __restrict__ bias,
                                                      float* __restrict__ Cout,
                                                      int M, int N, int K) {
  constexpr int BM = 64, BK = 128;
  __shared__ short As[2][BM * BK];   // 16 KB per buf
  __shared__ short Bs[2][BM * BK];
  const int tid = threadIdx.x;
  const int w = tid >> 6, lane = tid & 63;
  const int wm = w >> 1, wn = w & 1;
  const int l15 = lane & 15, l4 = lane >> 4;
  const int m0 = blockIdx.x * BM, n0 = blockIdx.y * BM;

  f32x4 acc[2][2] = {};

  // tile = 64 rows x 16 segs(16B); idx = row*16 + physseg
  int srow[4], scol[4];
#pragma unroll
  for (int i = 0; i < 4; i++) {
    const int idx = i * 256 + tid;
    const int row = idx >> 4, sp = idx & 15, sl = sp ^ (row & 15);
    srow[i] = row;
    scol[i] = sl * 8;
  }

#define FC_STAGE(bu, k0)                                                         \
  {                                                                              \
    _Pragma("unroll") for (int i = 0; i < 4; i++) {                              \
      const int idx = i * 256 + tid;                                             \
      gload_lds16(A + (size_t)(m0 + srow[i]) * K + (k0) + scol[i],               \
                  (char*)&As[bu][0] + idx * 16);                                 \
      gload_lds16(Bt + (size_t)(n0 + srow[i]) * K + (k0) + scol[i],              \
                  (char*)&Bs[bu][0] + idx * 16);                                 \
    }                                                                            \
  }

  FC_STAGE(0, 0);
  asm volatile("s_waitcnt vmcnt(0)" ::: "memory");
  __syncthreads();

  int bu = 0;
  for (int k0 = 0; k0 < K; k0 += BK) {
    if (k0 + BK < K) FC_STAGE(bu ^ 1, k0 + BK);

#pragma unroll
    for (int kst = 0; kst < 4; kst++) {
      const int sp = (kst * 4 + l4) ^ l15;
      bf16x8 af[2], bfr[2];
#pragma unroll
      for (int mt = 0; mt < 2; mt++)
        af[mt] = *(const bf16x8*)&As[bu][(wm * 32 + mt * 16 + l15) * 128 + sp * 8];
#pragma unroll
      for (int nt = 0; nt < 2; nt++)
        bfr[nt] = *(const bf16x8*)&Bs[bu][(wn * 32 + nt * 16 + l15) * 128 + sp * 8];
      __builtin_amdgcn_s_setprio(1);
#pragma unroll
      for (int mt = 0; mt < 2; mt++)
#pragma unroll
        for (int nt = 0; nt < 2; nt++)
          acc[mt][nt] = __builtin_amdgcn_mfma_f32_16x16x32_bf16(af[mt], bfr[nt], acc[mt][nt], 0, 0, 0);
      __builtin_amdgcn_s_setprio(0);
    }

    asm volatile("s_waitcnt vmcnt(0)" ::: "memory");
    __syncthreads();
    bu ^= 1;
  }

#pragma unroll
  for (int nt = 0; nt < 2; nt++) {
    const int n = n0 + wn * 32 + nt * 16 + l15;
    const float bvv = bias[n];
#pragma unroll
    for (int mt = 0; mt < 2; mt++) {
      const int mrow = m0 + wm * 32 + mt * 16 + 4 * l4;
      f32x4 v = acc[mt][nt];
#pragma unroll
      for (int r = 0; r < 4; r++)
        Cout[(size_t)(mrow + r) * N + n] = v[r] + bvv;
    }
  }
#undef FC_STAGE
}

// ---------------- causal flash attention (swapped QK^T softmax) --------------
// grid (48, 8), qt = 7 - blockIdx.y (heavy-first). 8 waves x 16 q-rows,
// KVBLK=32, dbuf K+V via pre-swizzled gload_lds (0 conflicts, R8-verified).
// T12 swapped QK; per-lane scalar m/l; P packed to bf16 by truncation (u>>16)
// and stored as uint2 (saves ~30 VALU + 6 LDS ops /tile/wave vs RNE f2bf).
__global__ __launch_bounds__(512) void attn_kernel(const short* __restrict__ Q,
                                                   const short* __restrict__ Kg,
                                                   const short* __restrict__ Vt,
                                                   short* __restrict__ Ctx) {
  __shared__ short Ks[2][8192];   // [4 kstp][32 kv][8 seg of 16B]
  __shared__ short Vs[2][8192];   // [128 dp][8 seg of 16B]
  __shared__ short Ps[8][512];    // per-wave [16 q][32 kv], seg-swizzled
  const int tid = threadIdx.x, w = tid >> 6, lane = tid & 63;
  const int l15 = lane & 15, l4 = lane >> 4;
  const int bh = blockIdx.x, b = bh / NH, h = bh % NH;
  const int qt = (gridDim.y - 1) - blockIdx.y;   // heavy-first
  const int q0 = qt * 128;
  const int qw0 = q0 + w * 16;
  const int ntiles = 4 * qt + 4;

  const float kMaskL2 = -14426.95f;   // -10000 * log2(e)
  const float kThrL2  = 11.5f;        // ~8 nats defer threshold

  const short* Kbase = Kg + (size_t)b * SEQ * EH + h * EMB;
  const short* Vbase = Vt + (size_t)bh * EMB * SEQ;

  int koff[2], voff[2];
#pragma unroll
  for (int i = 0; i < 2; i++) {
    const int idx = i * 512 + tid;     // [0, 1024)
    {
      const int kv = (idx >> 3) & 31, sp = idx & 7, sl = sp ^ (kv & 7);
      koff[i] = kv * EH + (idx >> 8) * 64 + sl * 8;
    }
    {
      const int dp = idx >> 3, sp = idx & 7, sl = sp ^ (dp & 7);
      voff[i] = (dp * 2 + (sl >> 2)) * SEQ + (sl & 3) * 8;
    }
  }

  bf16x8 qf[8];
  {
    const short* qp = Q + (size_t)(b * SEQ + qw0 + l15) * EH + h * EMB + 8 * l4;
#pragma unroll
    for (int kst = 0; kst < 8; kst++) qf[kst] = *(const bf16x8*)(qp + 32 * kst);
  }

  // prologue: stage tile 0 -> buf 0
#pragma unroll
  for (int i = 0; i < 2; i++) {
    const int idx = i * 512 + tid;
    gload_lds16(Kbase + koff[i], (char*)&Ks[0][0] + idx * 16);
    gload_lds16(Vbase + voff[i], (char*)&Vs[0][0] + idx * 16);
  }
  asm volatile("s_waitcnt vmcnt(0)" ::: "memory");
  __syncthreads();

  f32x4 o[16] = {};
  float mst = -1e30f, lst = 0.f;   // per-lane scalars (q = qw0 + l15)

  int bu = 0;
  for (int t = 0; t < ntiles; t++) {
    const int kv0 = t * 32;

    // ---- issue next-tile stage into buf^1 (hides under compute) ----
    if (t + 1 < ntiles) {
      const short* kp = Kbase + (size_t)(kv0 + 32) * EH;
      const short* vp = Vbase + kv0 + 32;
#pragma unroll
      for (int i = 0; i < 2; i++) {
        const int idx = i * 512 + tid;
        gload_lds16(kp + koff[i], (char*)&Ks[bu ^ 1][0] + idx * 16);
        gload_lds16(vp + voff[i], (char*)&Vs[bu ^ 1][0] + idx * 16);
      }
    }

    if (kv0 <= qw0 + 15) {   // wave-uniform: skip fully-masked tiles
      // ---- S = K Q^T (swapped): row=kv=4*l4+r, col=q=l15 ----
      f32x4 sf[2] = {};
      __builtin_amdgcn_s_setprio(1);
#pragma unroll
      for (int nt = 0; nt < 2; nt++)
#pragma unroll
        for (int kst = 0; kst < 8; kst++) {
          const int sp = (((kst & 1) << 2) + l4) ^ (l15 & 7);
          bf16x8 kf = *(const bf16x8*)&Ks[bu][(kst >> 1) * 2048 + (nt * 16 + l15) * 64 + sp * 8];
          sf[nt] = __builtin_amdgcn_mfma_f32_16x16x32_bf16(kf, qf[kst], sf[nt], 0, 0, 0);
        }
      __builtin_amdgcn_s_setprio(0);

      // ---- online softmax: per-lane scalar state, 2-shfl reduce ----
      const bool maskt = (kv0 + 31 > qw0);
      float sval[2][4];
      float mxl = -1e30f;
#pragma unroll
      for (int nt = 0; nt < 2; nt++)
#pragma unroll
        for (int r = 0; r < 4; r++) {
          float s = sf[nt][r];
          if (maskt) {
            const int kv = kv0 + nt * 16 + 4 * l4 + r;
            s += (kv > qw0 + l15) ? kMaskL2 : 0.0f;
          }
          sval[nt][r] = s;
          mxl = fmaxf(mxl, s);
        }
      float mx = fmaxf(mxl, __shfl_xor(mxl, 16));
      mx = fmaxf(mx, __shfl_xor(mx, 32));
      const bool skipt = __all(mx <= mst + kThrL2);
      float mref, fsc;
      if (skipt) {
        fsc = 1.0f;
        mref = mst;
      } else {
        float mnew = fmaxf(mst, mx);
        fsc = exp2f(mst - mnew);
        mst = mnew;
        mref = mnew;
      }
      float pp[2][4];
      float lsum = 0.f;
#pragma unroll
      for (int nt = 0; nt < 2; nt++)
#pragma unroll
        for (int r = 0; r < 4; r++) {
          float e = exp2f(sval[nt][r] - mref);
          pp[nt][r] = e;
          lsum += e;
        }
      lst = lst * fsc + lsum;   // partial over this lane's 8 kv; reduced at end

      if (!skipt) {
        // broadcast fsc of o-row (4*l4+r) from its l15-owner lane
        float fv[4];
#pragma unroll
        for (int r = 0; r < 4; r++)
          fv[r] = __shfl(fsc, (lane & 48) + 4 * (lane >> 4) + r);
#pragma unroll
        for (int nt = 0; nt < 16; nt++) {
          o[nt][0] *= fv[0]; o[nt][1] *= fv[1];
          o[nt][2] *= fv[2]; o[nt][3] *= fv[3];
        }
      }

      // ---- P -> per-wave LDS, truncation-packed uint2 stores ----
#pragma unroll
      for (int nt = 0; nt < 2; nt++) {
        uint2 pk;
        pk.x = pack_trunc(pp[nt][0], pp[nt][1]);
        pk.y = pack_trunc(pp[nt][2], pp[nt][3]);
        const int col0 = nt * 16 + 4 * l4;
        const int pseg = (col0 >> 3) ^ ((l15 >> 1) & 3);
        *(uint2*)&Ps[w][l15 * 32 + pseg * 8 + (col0 & 7)] = pk;
      }

      // ---- O += P V (V from LDS, conflict-free) ----
      const int aseg = l4 ^ ((l15 >> 1) & 3);
      bf16x8 af = *(const bf16x8*)&Ps[w][l15 * 32 + aseg * 8];
      const int vsp = ((l15 & 1) * 4 + l4) ^ (l15 >> 1);
      __builtin_amdgcn_s_setprio(1);
#pragma unroll
      for (int nt = 0; nt < 16; nt++) {
        const int dp = nt * 8 + (l15 >> 1);
        bf16x8 vf = *(const bf16x8*)&Vs[bu][dp * 64 + vsp * 8];
        o[nt] = __builtin_amdgcn_mfma_f32_16x16x32_bf16(af, vf, o[nt], 0, 0, 0);
      }
      __builtin_amdgcn_s_setprio(0);
    }

    // ---- single per-tile sync: next stage complete + all reads done ----
    asm volatile("s_waitcnt vmcnt(0)" ::: "memory");
    __syncthreads();
    bu ^= 1;
  }

  // ---- reduce distributed l (butterfly -> all lanes), broadcast inv ----
  lst += __shfl_xor(lst, 16);
  lst += __shfl_xor(lst, 32);
  const float inv = 1.f / lst;
  float invv[4];
#pragma unroll
  for (int r = 0; r < 4; r++)
    invv[r] = __shfl(inv, (lane & 48) + 4 * (lane >> 4) + r);

  const int mrow = b * SEQ + qw0 + 4 * l4;
#pragma unroll
  for (int nt = 0; nt < 16; nt++) {
    const int d = h * EMB + nt * 16 + l15;
#pragma unroll
    for (int r = 0; r < 4; r++)
      Ctx[(size_t)(mrow + r) * EH + d] = f2bf(o[nt][r] * invv[r]);
  }
}

extern "C" void kernel_launch(void* const* d_in, const int* in_sizes, int n_in,
                              void* d_out, int out_size, void* d_ws, size_t ws_size,
                              hipStream_t stream) {
  const float* x   = (const float*)d_in[0];
  const float* Wq  = (const float*)d_in[2];
  const float* bq  = (const float*)d_in[3];
  const float* Wk  = (const float*)d_in[4];
  const float* bk  = (const float*)d_in[5];
  const float* Wv  = (const float*)d_in[6];
  const float* bv  = (const float*)d_in[7];
  const float* Wfc = (const float*)d_in[8];
  const float* bfc = (const float*)d_in[9];
  float* out = (float*)d_out;

  short* ws    = (short*)d_ws;
  short* xb    = ws;                  // 4096*256
  short* wqkvt = xb + 1048576;        // 3*3072*256 contiguous [9216][256]
  short* wfct  = wqkvt + 3 * 786432;  // 256*3072
  short* q     = wfct + 786432;       // 4096*3072 (pre-scaled by log2e/16)
  short* k     = q + 12582912;
  short* vt    = k + 12582912;        // [b][h][d][s]
  short* ctx   = vt + 12582912;       // 4096*3072

  cast_x_kernel<<<1024, 256, 0, stream>>>(x, xb);
  transpose_qkv_kernel<<<dim3(EH / 32, EMB / 32, 3), 256, 0, stream>>>(Wq, Wk, Wv, wqkvt);
  transpose_cast_kernel<<<dim3(EMB / 32, EH / 32), 256, 0, stream>>>(Wfc, wfct, EH, EMB);

  qkv_gemm_kernel<<<dim3(MROWS / 128, 9216 / 128), 256, 0, stream>>>(
      xb, wqkvt, bq, bk, bv, q, k, vt);

  attn_kernel<<<dim3(BATCH * NH, SEQ / 128), 512, 0, stream>>>(q, k, vt, ctx);

  fc_gemm_kernel<<<dim3(MROWS / 64, EMB / 64), 256, 0, stream>>>(ctx, wfct, bfc, out, MROWS, EMB, EH);
}